// Round 6
// baseline (801.707 us; speedup 1.0000x reference)
//
#include <hip/hip_runtime.h>
#include <hip/hip_bf16.h>
#include <math.h>

#define OBS 512
#define MSG 2048
#define TAU 576
#define TAUP 640      // padded taus row stride
#define QN 16320
#define X2W 16896
#define INW 3136
#define PIW 2560

typedef short short8v __attribute__((ext_vector_type(8)));
typedef float f32x4 __attribute__((ext_vector_type(4)));

__device__ inline unsigned short bfbits(float x) {
  __hip_bfloat16 h = __float2bfloat16(x);
  return *reinterpret_cast<unsigned short*>(&h);
}

__device__ inline void gload16(const void* g, void* l) {
  __builtin_amdgcn_global_load_lds((__attribute__((address_space(1))) void*)(g),
                                   (__attribute__((address_space(3))) void*)(l), 16, 0, 0);
}

// barrier with LDS-write drain; vmcnt deliberately NOT drained (counted pipeline).
__device__ inline void bar_lgkm() {
  __builtin_amdgcn_sched_barrier(0);
  asm volatile("s_waitcnt lgkmcnt(0)" ::: "memory");
  __builtin_amdgcn_s_barrier();
  __builtin_amdgcn_sched_barrier(0);
}

// ---------------- bf16-MFMA NT matmul, 3-deep pipelined, on-the-fly fp32->bf16 W -----
// C[m,n] = act(sum_k A[m,k]*W[n,k] + bias[n]); A bf16 (lda), W fp32 (ldw). BN=64 BK=64,
// 8 waves. A: global_load_lds (pre-swizzled src, linear LDS). W: global->reg (issued 2
// steps early) -> cvt -> swizzled ds_write (1 step early). Reg-dep on B(t+1) gives a
// counted vmcnt wait (6 outstanding), loads span barriers (T3/T4).
// Hazards: stageA(t+2) overwrites buf (t-1)%3, last read compute(t-1) -> BARRIER_A.
//          writeB(t+1) overwrites buf (t-2)%3, last read compute(t-2) -> 2 barriers back.
//          compute(t) needs all waves' writeB(t)+A(t): done before iter t-1 BARRIER_B.
struct MMSet {
  const __hip_bfloat16* A;
  const float* W;
  const float* bias;
  float* C;
  __hip_bfloat16* Cb;
  int lda, ldw, ldc, ldcb;
};

template<int BM, int ACT, bool ATOMIC, bool DUAL>
__global__ __launch_bounds__(512)
void k_mm(MMSet s0, MMSet s1, int kSteps)
{
  constexpr int AREP = BM / 64;
  __shared__ __hip_bfloat16 As[3][BM * 64];
  __shared__ __hip_bfloat16 Bs[3][64 * 64];
  const MMSet S = (DUAL && blockIdx.z) ? s1 : s0;
  const int tid = threadIdx.x;
  const int lane = tid & 63;
  const int wid = tid >> 6;
  const int m0 = blockIdx.y * BM;
  const int n0 = blockIdx.x * 64;
  const size_t k0 = ATOMIC ? (size_t)blockIdx.z * kSteps * 64 : 0;

  const __hip_bfloat16* Ab = S.A + (size_t)m0 * S.lda + k0;
  const float* Bb = S.W + (size_t)n0 * S.ldw + k0;

  // A staging map: BM*8 chunks of 16B (8 bf16); LDS linear, global col XOR-swizzled.
  int arow[AREP], acol[AREP], adst[AREP];
#pragma unroll
  for (int r = 0; r < AREP; ++r) {
    int chunk = r * 512 + tid;
    arow[r] = chunk >> 3;
    acol[r] = ((chunk & 7) ^ (arow[r] & 7)) * 8;
    adst[r] = chunk * 8;
  }
  // W staging map: 1024 fp32 chunks of 16B (4 floats); dest = swizzled 8B slot.
  int brow[2], bcol[2], bdst[2];
#pragma unroll
  for (int r = 0; r < 2; ++r) {
    int c = r * 512 + tid;
    brow[r] = c >> 4;
    int g = (c & 15) >> 1, half = c & 1;
    bcol[r] = (c & 15) * 4;
    bdst[r] = brow[r] * 64 + ((g ^ (brow[r] & 7)) << 3) + half * 4;
  }

  const int wr = wid >> 1, wc = wid & 1;
  const int fr = lane & 15, q = lane >> 4;
  const int xm = fr & 7;

  f32x4 acc[AREP][2] = {};
  float4 p0a, p0b, p1a, p1b;          // two named reg sets (rule #20: no dyn index)

  auto stageA = [&](int buf, int kt) {
#pragma unroll
    for (int r = 0; r < AREP; ++r)
      gload16(Ab + (size_t)arow[r] * S.lda + kt + acol[r], &As[buf][adst[r]]);
  };
  auto loadB0 = [&](int kt) {
    p0a = *(const float4*)(Bb + (size_t)brow[0] * S.ldw + kt + bcol[0]);
    p0b = *(const float4*)(Bb + (size_t)brow[1] * S.ldw + kt + bcol[1]);
  };
  auto loadB1 = [&](int kt) {
    p1a = *(const float4*)(Bb + (size_t)brow[0] * S.ldw + kt + bcol[0]);
    p1b = *(const float4*)(Bb + (size_t)brow[1] * S.ldw + kt + bcol[1]);
  };
  auto writeB0 = [&](int buf) {
    ushort4 w0, w1;
    w0.x = bfbits(p0a.x); w0.y = bfbits(p0a.y); w0.z = bfbits(p0a.z); w0.w = bfbits(p0a.w);
    w1.x = bfbits(p0b.x); w1.y = bfbits(p0b.y); w1.z = bfbits(p0b.z); w1.w = bfbits(p0b.w);
    *(ushort4*)&Bs[buf][bdst[0]] = w0;
    *(ushort4*)&Bs[buf][bdst[1]] = w1;
  };
  auto writeB1 = [&](int buf) {
    ushort4 w0, w1;
    w0.x = bfbits(p1a.x); w0.y = bfbits(p1a.y); w0.z = bfbits(p1a.z); w0.w = bfbits(p1a.w);
    w1.x = bfbits(p1b.x); w1.y = bfbits(p1b.y); w1.z = bfbits(p1b.z); w1.w = bfbits(p1b.w);
    *(ushort4*)&Bs[buf][bdst[0]] = w0;
    *(ushort4*)&Bs[buf][bdst[1]] = w1;
  };

  // prologue: A0,B0,A1,B1 issued; B(k) lives in reg set k&1. writeB0 reg-dep => A0 done.
  stageA(0, 0); loadB0(0);
  if (kSteps > 1) { stageA(1, 64); loadB1(64); }
  writeB0(0);

  for (int t = 0; t < kSteps; ++t) {
    bar_lgkm();                                        // BARRIER_A
    if (t + 2 < kSteps) {
      stageA((t + 2) % 3, (t + 2) * 64);
      if (t & 1) loadB1((t + 2) * 64); else loadB0((t + 2) * 64);
    }
    if (t + 1 < kSteps) {
      if (t & 1) writeB0((t + 1) % 3); else writeB1((t + 1) % 3);
    }
    bar_lgkm();                                        // BARRIER_B
    const __hip_bfloat16* Ac = As[t % 3];
    const __hip_bfloat16* Bc = Bs[t % 3];
    __builtin_amdgcn_s_setprio(1);
#pragma unroll
    for (int ks = 0; ks < 2; ++ks) {
      const int cc = ks * 4 + q;
      const int co = ((cc ^ xm) << 3);
      short8v b0 = *(const short8v*)&Bc[(wc * 32 +  0 + fr) * 64 + co];
      short8v b1 = *(const short8v*)&Bc[(wc * 32 + 16 + fr) * 64 + co];
#pragma unroll
      for (int i = 0; i < AREP; ++i) {
        short8v a = *(const short8v*)&Ac[(wr * (AREP * 16) + i * 16 + fr) * 64 + co];
        acc[i][0] = __builtin_amdgcn_mfma_f32_16x16x32_bf16(a, b0, acc[i][0], 0, 0, 0);
        acc[i][1] = __builtin_amdgcn_mfma_f32_16x16x32_bf16(a, b1, acc[i][1], 0, 0, 0);
      }
    }
    __builtin_amdgcn_s_setprio(0);
  }

#pragma unroll
  for (int i = 0; i < AREP; ++i) {
    const int mb = m0 + wr * (AREP * 16) + i * 16 + q * 4;
#pragma unroll
    for (int j = 0; j < 2; ++j) {
      const int n = n0 + wc * 32 + j * 16 + fr;
      if (ATOMIC) {
#pragma unroll
        for (int v = 0; v < 4; ++v)
          atomicAdd(&S.C[(size_t)(mb + v) * S.ldc + n], acc[i][j][v]);
      } else {
        const float bb = S.bias[n];
#pragma unroll
        for (int v = 0; v < 4; ++v) {
          float val = acc[i][j][v] + bb;
          if (ACT) val = fmaxf(val, 0.f);
          if (S.C)  S.C[(size_t)(mb + v) * S.ldc + n] = val;
          if (S.Cb) S.Cb[(size_t)(mb + v) * S.ldcb + n] = __float2bfloat16(val);
        }
      }
    }
  }
}

// ---------------- fused init: hidden split + taus slabs + msg cvt + bias prefill ------
__global__ __launch_bounds__(256)
void k_init(const float* __restrict__ in, const float* __restrict__ hid,
            float* __restrict__ h32a, float* __restrict__ h32o, float* __restrict__ h32p,
            __hip_bfloat16* __restrict__ hba, __hip_bfloat16* __restrict__ hbo,
            __hip_bfloat16* __restrict__ hbp, __hip_bfloat16* __restrict__ hbp0,
            __hip_bfloat16* __restrict__ taus, __hip_bfloat16* __restrict__ msgb,
            const float* __restrict__ fo1b, float* __restrict__ xb0, float* __restrict__ xb1)
{
  const int bx = blockIdx.x;
  if (bx < 3072) {                       // hidden split: 256x3072
    int idx = bx * 256 + threadIdx.x;
    int b = idx / 3072, c = idx % 3072;
    float v = hid[idx];
    __hip_bfloat16 hb = __float2bfloat16(v);
    int j = c & 1023;
    if (c < 1024)      { h32a[b * 1024 + j] = v; hba[b * 1024 + j] = hb; }
    else if (c < 2048) { h32o[b * 1024 + j] = v; hbo[b * 1024 + j] = hb; }
    else               { h32p[b * 1024 + j] = v; hbp[b * 1024 + j] = hb; hbp0[b * 1024 + j] = hb; }
  } else if (bx < 3072 + 1920) {         // taus slabs: 3*256*TAUP
    int idx = (bx - 3072) * 256 + threadIdx.x;
    int t = idx / (256 * TAUP);
    int r = (idx / TAUP) % 256;
    int c = idx % TAUP;
    float v = 0.f;
    if (t == 0 && c < TAU)
      v = (c < OBS) ? in[(size_t)r * INW + OBS + c]
                    : in[(size_t)r * INW + 2 * OBS + (c - OBS)];
    taus[idx] = __float2bfloat16(v);
  } else if (bx < 3072 + 1920 + 2048) {  // msg cvt: 256x2048
    int idx = (bx - 3072 - 1920) * 256 + threadIdx.x;
    int b = idx >> 11, c = idx & 2047;
    msgb[idx] = __float2bfloat16(in[(size_t)b * INW + 1088 + c]);
  } else {                               // fo_fc1 bias prefill for both iters
    int idx = (bx - 3072 - 1920 - 2048) * 256 + threadIdx.x;  // 256*1024
    float v = fo1b[idx & 1023];
    xb0[idx] = v; xb1[idx] = v;
  }
}

// ---------------- GRU elementwise (fp32 math, dual fp32+bf16 out) ----------------
__global__ __launch_bounds__(256)
void k_gru(const float* __restrict__ gi, const float* __restrict__ gh,
           const float* __restrict__ hs, int ldsrc,
           float* __restrict__ hd, int lddst, __hip_bfloat16* __restrict__ hb)
{
  int idx = blockIdx.x * 256 + threadIdx.x;     // 256*1024
  int b = idx >> 10, j = idx & 1023;
  float ir = gi[b * 3072 + j];
  float iz = gi[b * 3072 + 1024 + j];
  float in_ = gi[b * 3072 + 2048 + j];
  float hr = gh[b * 3072 + j];
  float hz = gh[b * 3072 + 1024 + j];
  float hn = gh[b * 3072 + 2048 + j];
  float r = 1.f / (1.f + expf(-(ir + hr)));
  float z = 1.f / (1.f + expf(-(iz + hz)));
  float n = tanhf(in_ + r * hn);
  float h = hs[(size_t)b * ldsrc + j];
  float o = (1.f - z) * n + z * h;
  hd[(size_t)b * lddst + j] = o;
  hb[idx] = __float2bfloat16(o);
}

// softmax over 64-wide groups of q (bf16, stride QN), scatter (bf16) into x2
__global__ __launch_bounds__(256)
void k_softmax_scatter(const __hip_bfloat16* __restrict__ q, __hip_bfloat16* __restrict__ x2)
{
  int wid = blockIdx.x * 4 + (threadIdx.x >> 6);
  int lane = threadIdx.x & 63;
  int b = wid / 255, p = wid % 255;
  float v = __bfloat162float(q[(size_t)b * QN + p * 64 + lane]);
  float m = v;
#pragma unroll
  for (int s = 32; s; s >>= 1) m = fmaxf(m, __shfl_xor(m, s));
  float e = expf(v - m);
  float sum = e;
#pragma unroll
  for (int s = 32; s; s >>= 1) sum += __shfl_xor(sum, s);
  float r = e / sum;
  int flat = p * 16384 + b * 64 + lane;
  int bp = flat / QN;
  int j = flat - bp * QN;
  x2[(size_t)bp * X2W + j] = __float2bfloat16(r);
}

__global__ __launch_bounds__(256)
void k_x2_tail(const __hip_bfloat16* __restrict__ taus_t, __hip_bfloat16* __restrict__ x2)
{
  int idx = blockIdx.x * 256 + threadIdx.x;   // 256*576
  int b = idx / TAU, c = idx % TAU;
  if (c < 64)
    x2[(size_t)b * X2W + QN + c] = taus_t[(size_t)b * TAUP + OBS + c];
  else
    x2[(size_t)b * X2W + QN + 64 + (c - 64)] = taus_t[(size_t)b * TAUP + (c - 64)];
}

__global__ __launch_bounds__(256)
void k_concat_pi_loop(const __hip_bfloat16* __restrict__ taus_t,
                      const __hip_bfloat16* __restrict__ msg,
                      __hip_bfloat16* __restrict__ piin)
{
  int idx = blockIdx.x * 256 + threadIdx.x;   // 256*2560
  int b = idx / PIW, c = idx % PIW;
  piin[idx] = (c < OBS) ? taus_t[(size_t)b * TAUP + c] : msg[b * MSG + (c - OBS)];
}

__global__ __launch_bounds__(256)
void k_concat_pi_final(const float* __restrict__ in, const float* __restrict__ nm,
                       __hip_bfloat16* __restrict__ piin)
{
  int idx = blockIdx.x * 256 + threadIdx.x;
  int b = idx / PIW, c = idx % PIW;
  float v = (c < OBS) ? in[(size_t)b * INW + c] : nm[c - OBS];
  piin[idx] = __float2bfloat16(v);
}

__global__ __launch_bounds__(256)
void k_relu_cvt(const float* __restrict__ s, __hip_bfloat16* __restrict__ d)
{
  int idx = blockIdx.x * 256 + threadIdx.x;
  d[idx] = __float2bfloat16(fmaxf(s[idx], 0.f));
}

__global__ __launch_bounds__(64)
void k_vv(const __hip_bfloat16* __restrict__ taus, const float* __restrict__ w,
          const float* __restrict__ bias, float* __restrict__ vv)
{
  int row = blockIdx.x;        // 0..767
  int lane = threadIdx.x;
  const __hip_bfloat16* tr = taus + (size_t)row * TAUP;
  for (int v = 0; v < 8; ++v) {
    float s = 0.f;
    for (int k = lane; k < TAU; k += 64) s += __bfloat162float(tr[k]) * w[v * TAU + k];
#pragma unroll
    for (int d = 32; d; d >>= 1) s += __shfl_xor(s, d);
    if (lane == 0) vv[row * 8 + v] = s + bias[v];
  }
}

__global__ __launch_bounds__(64)
void k_attn(const float* __restrict__ qv, const float* __restrict__ kk,
            const float* __restrict__ vv, float* __restrict__ nm,
            float* __restrict__ out_q)
{
  int b = blockIdx.x;
  int lane = threadIdx.x;
  const float* qb = qv + (size_t)b * 1024;
  float s[3];
#pragma unroll
  for (int t = 0; t < 3; ++t) {
    const float* kb = kk + (size_t)(t * 256 + b) * 1024;
    float acc = 0.f;
    for (int h = lane; h < 1024; h += 64) acc += qb[h] * kb[h];
#pragma unroll
    for (int d = 32; d; d >>= 1) acc += __shfl_xor(acc, d);
    s[t] = acc * (1.f / 32.f);
  }
  float m = fmaxf(s[0], fmaxf(s[1], s[2]));
  float e0 = expf(s[0] - m), e1 = expf(s[1] - m), e2 = expf(s[2] - m);
  float inv = 1.f / (e0 + e1 + e2);
  float a0 = e0 * inv, a1 = e1 * inv, a2 = e2 * inv;
  if (lane < 8) {
    float v = a0 * vv[(0 * 256 + b) * 8 + lane]
            + a1 * vv[(1 * 256 + b) * 8 + lane]
            + a2 * vv[(2 * 256 + b) * 8 + lane];
    nm[b * 8 + lane] = v;
    out_q[b * 72 + lane] = v;
  }
}

__global__ __launch_bounds__(256)
void k_copy_hout(const float* __restrict__ hfa, const float* __restrict__ hfo,
                 float* __restrict__ hout)
{
  int idx = blockIdx.x * 256 + threadIdx.x;   // 256*2048
  int b = idx / 2048, c = idx % 2048;
  float v = (c < 1024) ? hfa[b * 1024 + c] : hfo[b * 1024 + (c - 1024)];
  hout[(size_t)b * 3072 + c] = v;
}

extern "C" void kernel_launch(void* const* d_in, const int* in_sizes, int n_in,
                              void* d_out_v, int out_size, void* d_ws, size_t ws_size,
                              hipStream_t stream)
{
  const float* inputs   = (const float*)d_in[0];
  const float* hidden   = (const float*)d_in[1];
  const float* pi_fc1_w = (const float*)d_in[2];
  const float* pi_fc1_b = (const float*)d_in[3];
  const float* pi_fc2_w = (const float*)d_in[4];
  const float* pi_fc2_b = (const float*)d_in[5];
  const float* fa_fc1_w = (const float*)d_in[6];
  const float* fa_fc1_b = (const float*)d_in[7];
  const float* fa_fc2_w = (const float*)d_in[8];
  const float* fa_fc2_b = (const float*)d_in[9];
  const float* fo_fc1_w = (const float*)d_in[10];
  const float* fo_fc1_b = (const float*)d_in[11];
  const float* fo_fc2_w = (const float*)d_in[12];
  const float* fo_fc2_b = (const float*)d_in[13];
  const float* am_qs_w  = (const float*)d_in[14];
  const float* am_qs_b  = (const float*)d_in[15];
  const float* am_ks_w  = (const float*)d_in[16];
  const float* am_ks_b  = (const float*)d_in[17];
  const float* am_vs_w  = (const float*)d_in[18];
  const float* am_vs_b  = (const float*)d_in[19];
  const float* pi_wih   = (const float*)d_in[20];
  const float* pi_bih   = (const float*)d_in[21];
  const float* pi_whh   = (const float*)d_in[22];
  const float* pi_bhh   = (const float*)d_in[23];
  const float* fa_wih   = (const float*)d_in[24];
  const float* fa_bih   = (const float*)d_in[25];
  const float* fa_whh   = (const float*)d_in[26];
  const float* fa_bhh   = (const float*)d_in[27];
  const float* fo_wih   = (const float*)d_in[28];
  const float* fo_bih   = (const float*)d_in[29];
  const float* fo_whh   = (const float*)d_in[30];
  const float* fo_bhh   = (const float*)d_in[31];

  float* out = (float*)d_out_v;
  char* p = (char*)d_ws;
  auto alloc = [&](size_t bytes) { void* r = p; p += (bytes + 255) & ~(size_t)255; return r; };
  typedef __hip_bfloat16 bf;

  // bf16 activations
  bf* HFAB = (bf*)alloc((size_t)256 * 1024 * 2);
  bf* HFOB = (bf*)alloc((size_t)256 * 1024 * 2);
  bf* HPIB = (bf*)alloc((size_t)256 * 1024 * 2);
  bf* HPI0B = (bf*)alloc((size_t)256 * 1024 * 2);
  bf* XBUFB = (bf*)alloc((size_t)256 * 1024 * 2);
  bf* TAUSB = (bf*)alloc((size_t)3 * 256 * TAUP * 2);
  bf* X2B  = (bf*)alloc((size_t)256 * X2W * 2);
  bf* PIINB = (bf*)alloc((size_t)256 * PIW * 2);
  bf* MSGB = (bf*)alloc((size_t)256 * MSG * 2);
  bf* QBUFB = (bf*)alloc((size_t)256 * QN * 2);
  // fp32
  float* HFA32 = (float*)alloc((size_t)256 * 1024 * 4);
  float* HFO32 = (float*)alloc((size_t)256 * 1024 * 4);
  float* HPI32 = (float*)alloc((size_t)256 * 1024 * 4);
  float* XBUF32A = (float*)alloc((size_t)256 * 1024 * 4);
  float* XBUF32B = (float*)alloc((size_t)256 * 1024 * 4);
  float* GI = (float*)alloc((size_t)256 * 3072 * 4);
  float* GH = (float*)alloc((size_t)256 * 3072 * 4);
  float* QV = (float*)alloc((size_t)256 * 1024 * 4);
  float* KK = (float*)alloc((size_t)768 * 1024 * 4);
  float* VV = (float*)alloc((size_t)768 * 8 * 4);
  float* NM = (float*)alloc((size_t)2048 * 4);

  auto mset = [&](const bf* A, int lda, const float* W, int ldw, const float* bias,
                  float* C, int ldc, bf* Cb, int ldcb) {
    MMSet s; s.A = A; s.W = W; s.bias = bias; s.C = C; s.Cb = Cb;
    s.lda = lda; s.ldw = ldw; s.ldc = ldc; s.ldcb = ldcb; return s;
  };
  auto mm256 = [&](MMSet a, int M, int N, int K) {
    dim3 g(N / 64, M / 256, 1);
    k_mm<256, 0, false, false><<<g, 512, 0, stream>>>(a, a, K / 64);
  };
  auto mm128 = [&](MMSet a, int M, int N, int K, int act) {
    dim3 g(N / 64, M / 128, 1);
    if (act) k_mm<128, 1, false, false><<<g, 512, 0, stream>>>(a, a, K / 64);
    else     k_mm<128, 0, false, false><<<g, 512, 0, stream>>>(a, a, K / 64);
  };
  auto mm64 = [&](MMSet a, int N, int K, int act) {
    dim3 g(N / 64, 4, 1);
    if (act) k_mm<64, 1, false, false><<<g, 512, 0, stream>>>(a, a, K / 64);
    else     k_mm<64, 0, false, false><<<g, 512, 0, stream>>>(a, a, K / 64);
  };
  auto mmDual = [&](MMSet a, MMSet b, int N, int K) {
    dim3 g(N / 64, 1, 2);
    k_mm<256, 0, false, true><<<g, 512, 0, stream>>>(a, b, K / 64);
  };

  k_init<<<3072 + 1920 + 2048 + 1024, 256, 0, stream>>>(inputs, hidden,
      HFA32, HFO32, HPI32, HFAB, HFOB, HPIB, HPI0B, TAUSB, MSGB,
      fo_fc1_b, XBUF32A, XBUF32B);

  for (int t = 0; t < 2; ++t) {
    bf* taus_t = TAUSB + (size_t)t * 256 * TAUP;
    bf* taus_n = TAUSB + (size_t)(t + 1) * 256 * TAUP;
    float* xb32 = t ? XBUF32B : XBUF32A;
    // fa branch
    mm64(mset(taus_t, TAUP, fa_fc1_w, 512, fa_fc1_b, nullptr, 0, XBUFB, 1024), 1024, 512, 1);
    mmDual(mset(XBUFB, 1024, fa_wih, 1024, fa_bih, GI, 3072, nullptr, 0),
           mset(HFAB, 1024, fa_whh, 1024, fa_bhh, GH, 3072, nullptr, 0), 3072, 1024);
    k_gru<<<1024, 256, 0, stream>>>(GI, GH, HFA32, 1024, HFA32, 1024, HFAB);
    mm256(mset(HFAB, 1024, fa_fc2_w, 1024, fa_fc2_b, nullptr, 0, QBUFB, QN), 256, QN, 1024);
    // x2 = [scrambled softmax | a | o]
    k_x2_tail<<<576, 256, 0, stream>>>(taus_t, X2B);
    k_softmax_scatter<<<16320, 256, 0, stream>>>(QBUFB, X2B);
    // fo branch: split-K (z=12 x 22 steps), fp32 atomics onto bias-prefilled buf
    {
      dim3 g(16, 1, 12);
      MMSet s = mset(X2B, X2W, fo_fc1_w, X2W, fo_fc1_b, xb32, 1024, nullptr, 0);
      k_mm<256, 0, true, false><<<g, 512, 0, stream>>>(s, s, 22);
    }
    k_relu_cvt<<<1024, 256, 0, stream>>>(xb32, XBUFB);
    mmDual(mset(XBUFB, 1024, fo_wih, 1024, fo_bih, GI, 3072, nullptr, 0),
           mset(HFOB, 1024, fo_whh, 1024, fo_bhh, GH, 3072, nullptr, 0), 3072, 1024);
    k_gru<<<1024, 256, 0, stream>>>(GI, GH, HFO32, 1024, HFO32, 1024, HFOB);
    mm64(mset(HFOB, 1024, fo_fc2_w, 1024, fo_fc2_b, nullptr, 0, taus_n, TAUP), 512, 1024, 0);
    // pi branch
    k_concat_pi_loop<<<2560, 256, 0, stream>>>(taus_t, MSGB, PIINB);
    mm128(mset(PIINB, PIW, pi_fc1_w, PIW, pi_fc1_b, nullptr, 0, XBUFB, 1024), 256, 1024, PIW, 1);
    mmDual(mset(XBUFB, 1024, pi_wih, 1024, pi_bih, GI, 3072, nullptr, 0),
           mset(HPIB, 1024, pi_whh, 1024, pi_bhh, GH, 3072, nullptr, 0), 3072, 1024);
    k_gru<<<1024, 256, 0, stream>>>(GI, GH, HPI32, 1024, HPI32, 1024, HPIB);
    mm64(mset(HPIB, 1024, pi_fc2_w, 1024, pi_fc2_b, nullptr, 0, taus_n + OBS, TAUP), 64, 1024, 0);
  }

  // attention
  mm128(mset(MSGB, MSG, am_qs_w, MSG, am_qs_b, QV, 1024, nullptr, 0), 256, 1024, 2048, 0);
  mm256(mset(TAUSB, TAUP, am_ks_w, TAU, am_ks_b, KK, 1024, nullptr, 0), 768, 1024, TAU);
  k_vv<<<768, 64, 0, stream>>>(TAUSB, am_vs_w, am_vs_b, VV);
  k_attn<<<256, 64, 0, stream>>>(QV, KK, VV, NM, out);

  // final pi with original h_pi0
  k_concat_pi_final<<<2560, 256, 0, stream>>>(inputs, NM, PIINB);
  mm128(mset(PIINB, PIW, pi_fc1_w, PIW, pi_fc1_b, nullptr, 0, XBUFB, 1024), 256, 1024, PIW, 1);
  mmDual(mset(XBUFB, 1024, pi_wih, 1024, pi_bih, GI, 3072, nullptr, 0),
         mset(HPI0B, 1024, pi_whh, 1024, pi_bhh, GH, 3072, nullptr, 0), 3072, 1024);
  k_gru<<<1024, 256, 0, stream>>>(GI, GH, hidden + 2048, 3072,
                                  out + 256 * 72 + 2048, 3072, HPIB);
  mm64(mset(HPIB, 1024, pi_fc2_w, 1024, pi_fc2_b, out + 8, 72, nullptr, 0), 64, 1024, 0);
  k_copy_hout<<<2048, 256, 0, stream>>>(HFA32, HFO32, out + 256 * 72);
  (void)in_sizes; (void)n_in; (void)out_size; (void)ws_size;
}